// Round 8
// baseline (187.412 us; speedup 1.0000x reference)
//
#include <hip/hip_runtime.h>

// VQ-VAE codebook quantization — MFMA-screened, np-bit-exact (absmax 0 since R6).
// Screen: split-bf16 (xh+xl)(ch+cl) via mfma_f32_16x16x32_bf16, 3 terms;
// sound window W flags possible np-argmin ambiguity (~1%); flagged positions
// re-scanned with the R2-verified exact np fp32 pipeline.
//
// R8: kill all inter-wave coupling. One wave per workgroup (64 positions),
// 2048 blocks, ZERO cross-wave barriers. B fragments load straight from ws
// global into VGPRs (coalesced 16B, L1/L2-hot, register double-buffered) —
// no B-LDS, no staging barriers; k-loop is a free-running stream. x staged
// in a 16KB XOR-swizzled per-wave LDS tile (b128-aligned, <=2-way conflicts).

typedef short bf16x8 __attribute__((ext_vector_type(8)));
typedef float f32x4  __attribute__((ext_vector_type(4)));

#define KCODES 512
#define DDIM 64
#define HWSZ 4096
#define NPOS 131072
#define POSW 64              // positions per wave/block
#define NBLK (NPOS / POSW)   // 2048
#define OUT2_OFF 8388608

__device__ __forceinline__ unsigned short f2bf_rne(float f) {
    unsigned u = __builtin_bit_cast(unsigned, f);
    unsigned r = u + 0x7FFFu + ((u >> 16) & 1u);
    return (unsigned short)(r >> 16);
}
__device__ __forceinline__ float bf2f(unsigned short h) {
    unsigned u = ((unsigned)h) << 16;
    return __builtin_bit_cast(float, u);
}

// numpy pairwise_sum (n=64 branch) of rounded squares, fp32, no fma (prep).
__device__ __forceinline__ float np_sumsq64(const float* __restrict__ a) {
#pragma clang fp contract(off)
    float r0 = a[0]*a[0], r1 = a[1]*a[1], r2 = a[2]*a[2], r3 = a[3]*a[3];
    float r4 = a[4]*a[4], r5 = a[5]*a[5], r6 = a[6]*a[6], r7 = a[7]*a[7];
#pragma unroll
    for (int i = 8; i < 64; i += 8) {
        r0 += a[i+0]*a[i+0]; r1 += a[i+1]*a[i+1];
        r2 += a[i+2]*a[i+2]; r3 += a[i+3]*a[i+3];
        r4 += a[i+4]*a[i+4]; r5 += a[i+5]*a[i+5];
        r6 += a[i+6]*a[i+6]; r7 += a[i+7]*a[i+7];
    }
    return ((r0+r1)+(r2+r3)) + ((r4+r5)+(r6+r7));
}

// Prep: B-fragments (split bf16) in exact 16x16x32 B-operand layout + np cbsqr.
// ws: [0,128KB) frags [tile32][chunk2][split2][lane64][j8]; [128KB,+2KB) cbsqr.
__global__ __launch_bounds__(256) void vq_prep(
    const float* __restrict__ cb, unsigned short* __restrict__ wsb,
    float* __restrict__ wscb)
{
    if (blockIdx.x < 128) {
        int u = blockIdx.x * 256 + threadIdx.x;   // u = k*64 + d
        int k = u >> 6, d = u & 63;
        float c = cb[u];
        unsigned short ch = f2bf_rne(c);
        float clf = c - bf2f(ch);                  // exact
        unsigned short cl = f2bf_rne(clf);
        int tile = k >> 4, n = k & 15;
        int chunk = d >> 5, quad = (d >> 3) & 3, j = d & 7;
        int lane = quad * 16 + n;                  // B: lane holds B[k=q*8+j][n]
        size_t base = ((((size_t)tile*2 + chunk)*2 + 0)*64 + lane)*8 + j;
        wsb[base]       = (unsigned short)ch;
        wsb[base + 512] = (unsigned short)cl;      // split stride = 64*8
    } else {
        int k = (blockIdx.x - 128) * 256 + threadIdx.x;
        if (k < KCODES) wscb[k] = np_sumsq64(cb + k * DDIM);
    }
}

// Swizzled x-tile addressing: row p (0..63), chunk c (0..15 of 4 floats):
// float4 index = p*16 + (c ^ (p & 15)).  16B-aligned, <=2-way bank aliasing.
__device__ __forceinline__ int xchunk(int p, int c) {
    return p * 16 + (c ^ (p & 15));
}

__global__ __launch_bounds__(64, 2) void vq_main(
    const float* __restrict__ z, const float* __restrict__ cb,
    const unsigned short* __restrict__ wsb, const float* __restrict__ wscb,
    float* __restrict__ out)
{
#pragma clang fp contract(off)
    __shared__ float s_x[POSW * DDIM];     // 16 KB, XOR-swizzled
    __shared__ float s_cbsqr[KCODES];      // 2 KB
    __shared__ int   s_idx[POSW];          // 256 B

    const int ln = threadIdx.x;            // lane == position-in-wave
    const int m = ln & 15, q = ln >> 4;
    const int n0 = blockIdx.x * POSW;
    const long gbase = (long)(n0 >> 12) * (DDIM * HWSZ) + (n0 & 4095);
    float4* s_x4 = (float4*)s_x;

    // cbsqr -> LDS (8 coalesced loads/lane).
#pragma unroll
    for (int i = 0; i < 8; ++i) s_cbsqr[i * 64 + ln] = wscb[i * 64 + ln];

    // ---- phase 1: z -> swizzled x-tile (lane=pos dim is coalesced) ----
#pragma unroll
    for (int c = 0; c < 16; ++c) {
        float4 w;
        w.x = z[gbase + (long)(4*c + 0) * HWSZ + ln];
        w.y = z[gbase + (long)(4*c + 1) * HWSZ + ln];
        w.z = z[gbase + (long)(4*c + 2) * HWSZ + ln];
        w.w = z[gbase + (long)(4*c + 3) * HWSZ + ln];
        s_x4[xchunk(ln, c)] = w;
    }
    __syncthreads();   // single-wave: just a waitcnt drain, cheap

    // ---- phase 2a: np-exact xsqr, lane = position, from own row ----
    float my_xsqr;
    {
        float r0=0.f,r1=0.f,r2=0.f,r3=0.f,r4=0.f,r5=0.f,r6=0.f,r7=0.f;
#pragma unroll
        for (int k = 0; k < 8; ++k) {      // d = 8k..8k+7, k ascending (np)
            float4 A = s_x4[xchunk(ln, 2*k)];
            float4 B = s_x4[xchunk(ln, 2*k + 1)];
            r0 += A.x*A.x; r1 += A.y*A.y; r2 += A.z*A.z; r3 += A.w*A.w;
            r4 += B.x*B.x; r5 += B.y*B.y; r6 += B.z*B.z; r7 += B.w*B.w;
        }
        my_xsqr = ((r0+r1)+(r2+r3)) + ((r4+r5)+(r6+r7));
    }

    // ---- phase 2b: A-fragments (4 row-tiles x 2 K-chunks, split bf16) ----
    bf16x8 Ah[8], Al[8];
#pragma unroll
    for (int rt = 0; rt < 4; ++rt)
#pragma unroll
        for (int c = 0; c < 2; ++c) {
            int row = rt * 16 + m;                 // position
            int h0 = c * 8 + q * 2;                // chunk of d = c*32+q*8
            float4 F0 = s_x4[xchunk(row, h0)];
            float4 F1 = s_x4[xchunk(row, h0 + 1)];
            float xv[8] = {F0.x,F0.y,F0.z,F0.w,F1.x,F1.y,F1.z,F1.w};
            bf16x8 ah, al;
#pragma unroll
            for (int j = 0; j < 8; ++j) {
                unsigned short hh = f2bf_rne(xv[j]);
                float lo = xv[j] - bf2f(hh);       // exact
                ah[j] = (short)hh;
                al[j] = (short)f2bf_rne(lo);
            }
            Ah[rt*2 + c] = ah; Al[rt*2 + c] = al;
        }

    // ---- phase 3: screen all 512 codes; B frags straight from global,
    //      register double-buffered one tile ahead; NO barriers ----
    float m1[16], m2[16]; int t1[16];
#pragma unroll
    for (int i = 0; i < 16; ++i) { m1[i] = 3.4e38f; m2[i] = 3.4e38f; t1[i] = 0; }

    const unsigned short* wb = wsb + ln * 8;
#define LDFRAG(t, c, s) (*(const bf16x8*)(wb + ((((t)*2+(c))*2+(s)) << 9)))
    bf16x8 Bh0 = LDFRAG(0,0,0), Bl0 = LDFRAG(0,0,1);
    bf16x8 Bh1 = LDFRAG(0,1,0), Bl1 = LDFRAG(0,1,1);
    float cbv = s_cbsqr[m];

    for (int t = 0; t < 32; ++t) {
        bf16x8 nh0, nl0, nh1, nl1; float ncbv = 0.f;
        if (t < 31) {
            nh0 = LDFRAG(t+1,0,0); nl0 = LDFRAG(t+1,0,1);
            nh1 = LDFRAG(t+1,1,0); nl1 = LDFRAG(t+1,1,1);
            ncbv = s_cbsqr[(t+1)*16 + m];
        }
#pragma unroll
        for (int rt = 0; rt < 4; ++rt) {
            const f32x4 zac = {0.f, 0.f, 0.f, 0.f};
            f32x4 aP = __builtin_amdgcn_mfma_f32_16x16x32_bf16(Al[rt*2+0], Bh0, zac, 0,0,0);
            f32x4 aQ = __builtin_amdgcn_mfma_f32_16x16x32_bf16(Ah[rt*2+0], Bl0, zac, 0,0,0);
            f32x4 aR = __builtin_amdgcn_mfma_f32_16x16x32_bf16(Ah[rt*2+0], Bh0, zac, 0,0,0);
            aP = __builtin_amdgcn_mfma_f32_16x16x32_bf16(Al[rt*2+1], Bh1, aP, 0,0,0);
            aQ = __builtin_amdgcn_mfma_f32_16x16x32_bf16(Ah[rt*2+1], Bl1, aQ, 0,0,0);
            aR = __builtin_amdgcn_mfma_f32_16x16x32_bf16(Ah[rt*2+1], Bh1, aR, 0,0,0);
            f32x4 acc = (aP + aQ) + aR;
#pragma unroll
            for (int r = 0; r < 4; ++r) {
                float sc = fmaf(-2.f, acc[r], cbv);
                int cell = rt * 4 + r;
                bool lt = sc < m1[cell];
                m2[cell] = fminf(m2[cell], lt ? m1[cell] : sc);
                if (lt) { m1[cell] = sc; t1[cell] = t; }
            }
        }
        Bh0 = nh0; Bl0 = nl0; Bh1 = nh1; Bl1 = nl1; cbv = ncbv;
    }
#undef LDFRAG

    // ---- phase 4: reduce each cell over its 16 m-lanes; flag ambiguity ----
#pragma unroll
    for (int cell = 0; cell < 16; ++cell) {
        int rt = cell >> 2, r = cell & 3;
        float v1 = m1[cell], v2 = m2[cell];
        int i1 = t1[cell] * 16 + m;
#pragma unroll
        for (int s = 1; s < 16; s <<= 1) {
            float o1 = __shfl_xor(v1, s);
            float o2 = __shfl_xor(v2, s);
            int   oi = __shfl_xor(i1, s);
            bool take = (o1 < v1) || (o1 == v1 && oi < i1);
            float lose = take ? v1 : o1;
            if (take) { v1 = o1; i1 = oi; }
            v2 = fminf(fminf(v2, o2), lose);
        }
        int pos = rt * 16 + q * 4 + r;
        float xs = __shfl(my_xsqr, pos);           // all lanes active
        float sx = 8.0f * sqrtf(xs) * 1.01f;       // >= sum |x_d|
        float amax = 0.00196f * sx + 0.01f;        // >= sum|x c| + margin
        float eps = 1.5f * (3.0f * 1.52587890625e-5f * 0.00196f * sx
                            + 500.f * 5.96e-8f * amax);
        float delta = 2.4e-7f * (xs + 1.0f) + 64.f * 1.2e-7f * amax;
        float W = 2.f * eps + 2.f * delta + 1e-9f;
        int flag = (v2 - v1 <= W) ? (1 << 30) : 0;
        if (m == 0) s_idx[pos] = i1 | flag;        // 4 writer lanes (q=0..3)
    }
    __syncthreads();

    // ---- phase 5: np-exact refine of flagged positions (ballot-driven) ----
    int myidx = s_idx[ln];
    unsigned long long mask = __ballot(myidx & (1 << 30));
    while (mask) {
        int p = __builtin_ctzll(mask);
        mask &= mask - 1;
        // lane ln holds x[d=ln] of position p (from swizzled LDS tile).
        float xv = s_x[p * 64 + (((ln >> 2) ^ (p & 15)) << 2) + (ln & 3)];
        float xs = __shfl(my_xsqr, p);
        float dot[8];
#pragma unroll
        for (int j = 0; j < 8; ++j) dot[j] = 0.f;
        const float* crow = cb + (ln * 8) * DDIM;   // lane's 8 codes
        for (int dc = 0; dc < 16; ++dc) {
            float x0 = __shfl(xv, dc*4 + 0);
            float x1 = __shfl(xv, dc*4 + 1);
            float x2 = __shfl(xv, dc*4 + 2);
            float x3 = __shfl(xv, dc*4 + 3);
#pragma unroll
            for (int j = 0; j < 8; ++j) {
                float4 cv = *(const float4*)(crow + j * DDIM + dc * 4);
                dot[j] = fmaf(x0, cv.x, dot[j]);
                dot[j] = fmaf(x1, cv.y, dot[j]);
                dot[j] = fmaf(x2, cv.z, dot[j]);
                dot[j] = fmaf(x3, cv.w, dot[j]);
            }
        }
        float bv = 3.4e38f; int bi = 0;
#pragma unroll
        for (int j = 0; j < 8; ++j) {
            int k = ln * 8 + j;
            float tt = s_cbsqr[k] + xs;
            float e = fmaf(-2.f, dot[j], tt);
            if (e < bv) { bv = e; bi = k; }
        }
#pragma unroll
        for (int s = 1; s < 64; s <<= 1) {
            float ov = __shfl_xor(bv, s); int oi = __shfl_xor(bi, s);
            if (ov < bv || (ov == bv && oi < bi)) { bv = ov; bi = oi; }
        }
        if (ln == 0) s_idx[p] = bi;
    }
    __syncthreads();

    // ---- phase 6: scatter selected code to both outputs (NCHW) ----
    {
        int idx = s_idx[ln] & 0x3FFFFFFF;
        const float4* crow4 = (const float4*)(cb + idx * DDIM);
        float* o0 = out + gbase + ln;
        float* o1 = o0 + OUT2_OFF;
#pragma unroll
        for (int c = 0; c < 16; ++c) {
            float4 v = crow4[c];
            long db = (long)(c * 4) * HWSZ;
            o0[db]          = v.x; o0[db + HWSZ]   = v.y;
            o0[db + 2*HWSZ] = v.z; o0[db + 3*HWSZ] = v.w;
            o1[db]          = v.x; o1[db + HWSZ]   = v.y;
            o1[db + 2*HWSZ] = v.z; o1[db + 3*HWSZ] = v.w;
        }
    }
}

extern "C" void kernel_launch(void* const* d_in, const int* in_sizes, int n_in,
                              void* d_out, int out_size, void* d_ws, size_t ws_size,
                              hipStream_t stream) {
    const float* z  = (const float*)d_in[0];   // [32,64,64,64] fp32
    const float* cb = (const float*)d_in[1];   // [512,64] fp32
    float* out = (float*)d_out;                // 2 * 8388608 fp32
    unsigned short* wsb = (unsigned short*)d_ws;            // 128 KB frags
    float* wscb = (float*)((char*)d_ws + 131072);           // 2 KB cbsqr
    vq_prep<<<130, 256, 0, stream>>>(cb, wsb, wscb);
    vq_main<<<NBLK, 64, 0, stream>>>(z, cb, wsb, wscb, out);
}